// Round 3
// baseline (3463.349 us; speedup 1.0000x reference)
//
#include <hip/hip_runtime.h>
#include <math.h>

#define TT 2048

typedef __attribute__((ext_vector_type(8))) short bfrag;   // 8 bf16 in 4 VGPRs
typedef __attribute__((ext_vector_type(4))) float facc;    // 4 fp32 acc

#define NEG_BIG (-1.0e30f)

__device__ __forceinline__ unsigned short f2b(float f) {
    union { float f; unsigned int i; } v; v.f = f;
    unsigned int b = v.i;
    return (unsigned short)((b + 0x7FFFu + ((b >> 16) & 1u)) >> 16);  // RNE
}
// NaN-proof clamp: fminf first so NaN -> +1e30. Diagnostic firewall.
__device__ __forceinline__ float sanitize(float v) {
    return fmaxf(fminf(v, 1.0e30f), -1.0e30f);
}

// ---------------------------------------------------------------------------
// Dtype detector: reads first 4096 shorts of x. If the underlying data is
// fp32, odd-index shorts are fp32 low-mantissa bits (uniform random) and
// ~45% decode as |bf16| >= 2^14; true bf16 gaussian-scale data has none.
// flag=1 -> inputs are fp32.
// ---------------------------------------------------------------------------
__global__ __launch_bounds__(256) void k_detect(const unsigned short* __restrict__ x,
                                                int* __restrict__ flag) {
    __shared__ int s[256];
    int tid = threadIdx.x, cnt = 0;
    for (int i = tid; i < 4096; i += 256) {
        unsigned int e = (x[i] >> 7) & 0xFF;       // bf16 exponent field
        cnt += (e >= 141);                          // |v| >= 16384
    }
    s[tid] = cnt; __syncthreads();
    for (int st = 128; st > 0; st >>= 1) {
        if (tid < st) s[tid] += s[tid + st];
        __syncthreads();
    }
    if (tid == 0) *flag = (s[0] > 16) ? 1 : 0;
}

__device__ __forceinline__ void cvt8_f32(const float* __restrict__ p, unsigned short* d) {
    float4 lo = *(const float4*)p, hi = *(const float4*)(p + 4);
    d[0] = f2b(lo.x); d[1] = f2b(lo.y); d[2] = f2b(lo.z); d[3] = f2b(lo.w);
    d[4] = f2b(hi.x); d[5] = f2b(hi.y); d[6] = f2b(hi.z); d[7] = f2b(hi.w);
}

// ---------------------------------------------------------------------------
// GEMM: C (MxN,row-major) = A (MxK,row-major) @ B (KxN,row-major).
// 128x128 tile, BK=32, 4 waves, 4x4 16x16x32-bf16 MFMAs per wave.
// B transposed on the fly into LDS. Dual-dtype: selA/selB/selO pick whether
// the operand follows the detected global dtype (flag) or is always bf16.
// ---------------------------------------------------------------------------
__global__ __launch_bounds__(256) void k_gemm_bn(const void* __restrict__ A,
                                                 const void* __restrict__ B,
                                                 void* __restrict__ Cmat,
                                                 int M, int N, int K,
                                                 const int* __restrict__ flagp,
                                                 int selA, int selB, int selO) {
    __shared__ alignas(16) unsigned short As[128][40];
    __shared__ alignas(16) unsigned short Bs[128][40];
    int fl = *flagp;
    int aF = selA & fl, bF = selB & fl, oF = selO & fl;
    int tid = threadIdx.x;
    int w = tid >> 6, lane = tid & 63, quad = lane >> 4, l15 = lane & 15;
    int m0 = blockIdx.y * 128, n0 = blockIdx.x * 128;
    int wm = (w >> 1) * 64, wn = (w & 1) * 64;

    facc acc[4][4];
    for (int mi = 0; mi < 4; ++mi)
        for (int ni = 0; ni < 4; ++ni)
            for (int r = 0; r < 4; ++r) acc[mi][ni][r] = 0.f;

    for (int k0 = 0; k0 < K; k0 += 32) {
        for (int i = 0; i < 2; ++i) {
            int c = tid + i * 256;                       // 512 chunks of 8
            int arow = c >> 2, ak8 = (c & 3) * 8;
            if (aF) {
                unsigned short t[8];
                cvt8_f32((const float*)A + (size_t)(m0 + arow) * K + k0 + ak8, t);
                *(uint4*)&As[arow][ak8] = *(const uint4*)t;
            } else {
                *(uint4*)&As[arow][ak8] =
                    *(const uint4*)((const unsigned short*)A + (size_t)(m0 + arow) * K + k0 + ak8);
            }
            int kr = c >> 4, n8 = (c & 15) * 8;
            unsigned short t[8];
            if (bF) {
                cvt8_f32((const float*)B + (size_t)(k0 + kr) * N + n0 + n8, t);
            } else {
                *(uint4*)t = *(const uint4*)((const unsigned short*)B + (size_t)(k0 + kr) * N + n0 + n8);
            }
            for (int j = 0; j < 8; ++j) Bs[n8 + j][kr] = t[j];
        }
        __syncthreads();
        bfrag af[4], bf[4];
        for (int mi = 0; mi < 4; ++mi) af[mi] = *(const bfrag*)&As[wm + mi * 16 + l15][quad * 8];
        for (int ni = 0; ni < 4; ++ni) bf[ni] = *(const bfrag*)&Bs[wn + ni * 16 + l15][quad * 8];
        for (int mi = 0; mi < 4; ++mi)
            for (int ni = 0; ni < 4; ++ni)
                acc[mi][ni] = __builtin_amdgcn_mfma_f32_16x16x32_bf16(af[mi], bf[ni], acc[mi][ni], 0, 0, 0);
        __syncthreads();
    }
    // C/D layout: col = l15, row = quad*4 + r  [m89/m91 verified]
    for (int mi = 0; mi < 4; ++mi)
        for (int ni = 0; ni < 4; ++ni)
            for (int r = 0; r < 4; ++r) {
                int row = m0 + wm + mi * 16 + quad * 4 + r;
                int col = n0 + wn + ni * 16 + l15;
                float v = sanitize(acc[mi][ni][r]);
                if (oF) ((float*)Cmat)[(size_t)row * N + col] = v;
                else    ((unsigned short*)Cmat)[(size_t)row * N + col] = f2b(v);
            }
}

// ---------------------------------------------------------------------------
// RoPE in-place on bf16 X (B*T rows, nh*128 cols), repeat-2 freqs.
// ---------------------------------------------------------------------------
__global__ __launch_bounds__(256) void k_rope(unsigned short* __restrict__ X,
                                              int lognh, const int* __restrict__ posPtr) {
    int tid = blockIdx.x * 256 + threadIdx.x;
    int d = tid & 63;
    int nh = 1 << lognh;
    int h = (tid >> 6) & (nh - 1);
    int row = tid >> (6 + lognh);
    int t = row & (TT - 1);
    float p = (float)(*posPtr + t);
    size_t base = (size_t)row * (nh * 128) + h * 128 + d;
    union { unsigned int i; float f; } a, b2;
    a.i  = ((unsigned int)X[base]) << 16;
    b2.i = ((unsigned int)X[base + 64]) << 16;
    float x1 = a.f, x2 = b2.f;
    int i1 = d >> 1;
    float f1 = powf(10000.f, -(float)(2 * i1) / 128.f);
    float f2 = powf(10000.f, -(float)(2 * i1 + 64) / 128.f);
    float th1 = p * f1, th2 = p * f2;
    X[base]      = f2b(sanitize(x1 * cosf(th1) - x2 * sinf(th1)));
    X[base + 64] = f2b(sanitize(x2 * cosf(th2) + x1 * sinf(th2)));
}

// ---------------------------------------------------------------------------
// Flash attention, causal, GQA (16 q / 4 kv heads). Grid (T/64, B*16).
// All-bf16 ws buffers. In-place att==Q safe (disjoint (rows,head) slices).
// Finite sentinels; explicit p=0 on masked lanes.
// ---------------------------------------------------------------------------
__global__ __launch_bounds__(256) void k_flash(const unsigned short* __restrict__ Q,
                                               const unsigned short* __restrict__ Kb,
                                               const unsigned short* __restrict__ Vb,
                                               unsigned short* __restrict__ att) {
    __shared__ alignas(16) unsigned short Ks[32][136];
    __shared__ alignas(16) unsigned short Vt[128][40];
    __shared__ alignas(16) unsigned short Pt[4][16][40];
    int tid = threadIdx.x;
    int w = tid >> 6, lane = tid & 63, quad = lane >> 4, l15 = lane & 15;
    int bh = blockIdx.y;
    int b = bh >> 4, h = bh & 15;
    int kvh = h >> 2;
    int qbase = blockIdx.x * 64;

    bfrag qf[4];
    {
        size_t qrow = (size_t)(b * TT + qbase + w * 16 + l15);
        for (int kc = 0; kc < 4; ++kc)
            qf[kc] = *(const bfrag*)(Q + qrow * 2048 + h * 128 + kc * 32 + quad * 8);
    }
    float mrow[4], lrow[4];
    facc o[8];
    for (int r = 0; r < 4; ++r) { mrow[r] = NEG_BIG; lrow[r] = 0.f; }
    for (int nb2 = 0; nb2 < 8; ++nb2)
        for (int r = 0; r < 4; ++r) o[nb2][r] = 0.f;

    const float sc = 0.08838834764831845f;   // 1/sqrt(128)
    int kmax = qbase + 64;
    for (int k0 = 0; k0 < kmax; k0 += 32) {
        for (int i = 0; i < 2; ++i) {
            int c = tid + i * 256;
            int krow = c >> 4, d8 = (c & 15) * 8;
            size_t gbase = (size_t)(b * TT + k0 + krow) * 512 + kvh * 128 + d8;
            *(uint4*)&Ks[krow][d8] = *(const uint4*)(Kb + gbase);
            union { uint4 v; unsigned short s[8]; } u;
            u.v = *(const uint4*)(Vb + gbase);
            for (int j = 0; j < 8; ++j) Vt[d8 + j][krow] = u.s[j];
        }
        __syncthreads();

        facc s[2];
        for (int nb = 0; nb < 2; ++nb) {
            for (int r = 0; r < 4; ++r) s[nb][r] = 0.f;
            for (int kc = 0; kc < 4; ++kc) {
                bfrag kf = *(const bfrag*)&Ks[nb * 16 + l15][kc * 32 + quad * 8];
                s[nb] = __builtin_amdgcn_mfma_f32_16x16x32_bf16(qf[kc], kf, s[nb], 0, 0, 0);
            }
        }

        float pv0[4], pv1[4];
        for (int r = 0; r < 4; ++r) {
            int qg = qbase + w * 16 + quad * 4 + r;
            bool msk0 = (k0 + l15 > qg);
            bool msk1 = (k0 + 16 + l15 > qg);
            float v0 = msk0 ? NEG_BIG : sanitize(s[0][r] * sc);
            float v1 = msk1 ? NEG_BIG : sanitize(s[1][r] * sc);
            float mx = fmaxf(v0, v1);
            for (int off = 1; off < 16; off <<= 1) mx = fmaxf(mx, __shfl_xor(mx, off, 64));
            float mnew = fmaxf(mrow[r], mx);
            float alpha = __expf(mrow[r] - mnew);
            float p0 = msk0 ? 0.f : __expf(v0 - mnew);
            float p1 = msk1 ? 0.f : __expf(v1 - mnew);
            float psum = p0 + p1;
            for (int off = 1; off < 16; off <<= 1) psum += __shfl_xor(psum, off, 64);
            lrow[r] = lrow[r] * alpha + psum;
            mrow[r] = mnew;
            for (int nb2 = 0; nb2 < 8; ++nb2) o[nb2][r] *= alpha;
            pv0[r] = p0; pv1[r] = p1;
        }

        for (int r = 0; r < 4; ++r) {
            Pt[w][quad * 4 + r][l15]      = f2b(pv0[r]);
            Pt[w][quad * 4 + r][16 + l15] = f2b(pv1[r]);
        }
        __syncthreads();
        bfrag pf = *(const bfrag*)&Pt[w][l15][quad * 8];
        for (int nb2 = 0; nb2 < 8; ++nb2) {
            bfrag vf = *(const bfrag*)&Vt[nb2 * 16 + l15][quad * 8];
            o[nb2] = __builtin_amdgcn_mfma_f32_16x16x32_bf16(pf, vf, o[nb2], 0, 0, 0);
        }
        __syncthreads();
    }

    for (int nb2 = 0; nb2 < 8; ++nb2)
        for (int r = 0; r < 4; ++r) {
            int qg = qbase + w * 16 + quad * 4 + r;
            att[(size_t)(b * TT + qg) * 2048 + h * 128 + nb2 * 16 + l15] =
                f2b(sanitize(o[nb2][r] / lrow[r]));
        }
}

// ---------------------------------------------------------------------------
extern "C" void kernel_launch(void* const* d_in, const int* in_sizes, int n_in,
                              void* d_out, int out_size, void* d_ws, size_t ws_size,
                              hipStream_t stream) {
    const void* x  = d_in[0];
    const void* Wq = d_in[1];
    const void* Wk = d_in[2];
    const void* Wv = d_in[3];
    const void* Wo = d_in[4];
    const int* pos = (const int*)d_in[5];

    char* ws = (char*)d_ws;
    unsigned short* Qb = (unsigned short*)(ws + 0);          // 32 MB (8192x2048)
    unsigned short* Kb = (unsigned short*)(ws + 33554432);   //  8 MB (8192x512)
    unsigned short* Vb = (unsigned short*)(ws + 41943040);   //  8 MB
    int* flag          = (int*)(ws + 50331648);              // 48 MB + flag

    // dtype detection (fp32 vs bf16 inputs)
    k_detect<<<1, 256, 0, stream>>>((const unsigned short*)x, flag);

    // projections: A=x (flag dtype), B=W* (flag dtype), out=ws bf16
    k_gemm_bn<<<dim3(16, 64), 256, 0, stream>>>(x, Wq, Qb, 8192, 2048, 2048, flag, 1, 1, 0);
    k_gemm_bn<<<dim3(4, 64),  256, 0, stream>>>(x, Wk, Kb, 8192, 512,  2048, flag, 1, 1, 0);
    k_gemm_bn<<<dim3(4, 64),  256, 0, stream>>>(x, Wv, Vb, 8192, 512,  2048, flag, 1, 1, 0);

    // RoPE (Q: 16 heads, K: 4 heads) on bf16 ws buffers
    k_rope<<<32768, 256, 0, stream>>>(Qb, 4, pos);
    k_rope<<<8192,  256, 0, stream>>>(Kb, 2, pos);

    // causal GQA flash attention, in-place over Qb
    k_flash<<<dim3(32, 64), 256, 0, stream>>>(Qb, Kb, Vb, Qb);

    // output projection: A=ws bf16, B=Wo (flag), out=d_out (flag dtype)
    k_gemm_bn<<<dim3(16, 64), 256, 0, stream>>>(Qb, Wo, d_out, 8192, 2048, 2048, flag, 0, 1, 1);
}

// Round 4
// 1017.892 us; speedup vs baseline: 3.4025x; 3.4025x over previous
//
#include <hip/hip_runtime.h>
#include <math.h>

#define TT 2048

typedef __attribute__((ext_vector_type(8))) short bfrag;   // 8 bf16 in 4 VGPRs
typedef __attribute__((ext_vector_type(4))) float facc;    // 4 fp32 acc

#define NEG_BIG (-1.0e30f)

typedef __attribute__((address_space(1))) const void gas_void;
typedef __attribute__((address_space(3))) void las_void;

__device__ __forceinline__ void gl_lds16(const void* g, void* l) {
    __builtin_amdgcn_global_load_lds((gas_void*)g, (las_void*)l, 16, 0, 0);
}

__device__ __forceinline__ unsigned short f2b(float f) {
    union { float f; unsigned int i; } v; v.f = f;
    unsigned int b = v.i;
    return (unsigned short)((b + 0x7FFFu + ((b >> 16) & 1u)) >> 16);  // RNE
}
__device__ __forceinline__ void cvt8_f32(const float* __restrict__ p, unsigned short* d) {
    float4 lo = *(const float4*)p, hi = *(const float4*)(p + 4);
    d[0] = f2b(lo.x); d[1] = f2b(lo.y); d[2] = f2b(lo.z); d[3] = f2b(lo.w);
    d[4] = f2b(hi.x); d[5] = f2b(hi.y); d[6] = f2b(hi.z); d[7] = f2b(hi.w);
}

// ---------------------------------------------------------------------------
// fp32 -> bf16 flat convert (n8 = count of 8-element chunks)
// ---------------------------------------------------------------------------
__global__ __launch_bounds__(256) void k_cvt(const float* __restrict__ in,
                                             unsigned short* __restrict__ out, int n8) {
    int c = blockIdx.x * 256 + threadIdx.x;
    if (c < n8) {
        unsigned short t[8];
        cvt8_f32(in + (size_t)c * 8, t);
        *(uint4*)(out + (size_t)c * 8) = *(const uint4*)t;
    }
}

// ---------------------------------------------------------------------------
// Weight transpose+convert: W (2048 x N fp32, row-major) -> WT (N x 2048 bf16)
// 64x64 tiles via LDS.
// ---------------------------------------------------------------------------
__global__ __launch_bounds__(256) void k_wt(const float* __restrict__ W,
                                            unsigned short* __restrict__ WT, int N) {
    __shared__ alignas(16) unsigned short tile[64][72];
    int r0 = blockIdx.y * 64, c0 = blockIdx.x * 64;
    int tid = threadIdx.x;
    for (int i = 0; i < 2; ++i) {
        int c = tid + i * 256;
        int row = c >> 3, c8 = (c & 7) * 8;
        unsigned short t[8];
        cvt8_f32(W + (size_t)(r0 + row) * N + c0 + c8, t);
        *(uint4*)&tile[row][c8] = *(const uint4*)t;
    }
    __syncthreads();
    for (int i = 0; i < 2; ++i) {
        int c = tid + i * 256;
        int col = c >> 3, r8 = (c & 7) * 8;
        unsigned short t[8];
        for (int j = 0; j < 8; ++j) t[j] = tile[r8 + j][col];
        *(uint4*)(WT + (size_t)(c0 + col) * 2048 + r0 + r8) = *(const uint4*)t;
    }
}

// ---------------------------------------------------------------------------
// V transpose: KV (8192 x 1024 bf16, V = cols 512..1023) -> VbT (512 x 8192)
// ---------------------------------------------------------------------------
__global__ __launch_bounds__(256) void k_vt(const unsigned short* __restrict__ KV,
                                            unsigned short* __restrict__ VbT) {
    __shared__ alignas(16) unsigned short tile[64][72];
    int r0 = blockIdx.y * 64, c0 = blockIdx.x * 64;
    int tid = threadIdx.x;
    for (int i = 0; i < 2; ++i) {
        int c = tid + i * 256;
        int row = c >> 3, c8 = (c & 7) * 8;
        *(uint4*)&tile[row][c8] =
            *(const uint4*)(KV + (size_t)(r0 + row) * 1024 + 512 + c0 + c8);
    }
    __syncthreads();
    for (int i = 0; i < 2; ++i) {
        int c = tid + i * 256;
        int col = c >> 3, r8 = (c & 7) * 8;
        unsigned short t[8];
        for (int j = 0; j < 8; ++j) t[j] = tile[r8 + j][col];
        *(uint4*)(VbT + (size_t)(c0 + col) * 8192 + r0 + r8) = *(const uint4*)t;
    }
}

// ---------------------------------------------------------------------------
// m97-style GEMM: C (MxN) = A (MxK bf16) @ Bt^T (Bt: NxK bf16).
// 128x128 tile, BK=32, global_load_lds width=16 into unpadded [128][32]
// with XOR chunk swizzle (writer chunk=(lane&3)^((lane>>3)&3); reader slot
// =quad^((l15>>1)&3)) -> 2-way LDS conflicts only (free, m136).
// Coalesced LDS-staged epilogue; outF=1 writes fp32, else bf16.
// ---------------------------------------------------------------------------
__global__ __launch_bounds__(256) void k_gemm_bt(const unsigned short* __restrict__ A,
                                                 const unsigned short* __restrict__ Bt,
                                                 void* __restrict__ Cmat,
                                                 int M, int N, int K, int outF) {
    __shared__ union SM {
        struct { unsigned short A[128][32]; unsigned short B[128][32]; } s;  // 16 KB
        unsigned short ct[32][136];
        float          ctf[32][136];
    } sm;
    int tid = threadIdx.x;
    int w = tid >> 6, lane = tid & 63, quad = lane >> 4, l15 = lane & 15;
    int m0 = blockIdx.y * 128, n0 = blockIdx.x * 128;
    int wm = (w >> 1) * 64, wn = (w & 1) * 64;

    // staging geometry (wave-uniform LDS base; per-lane global address)
    int srow   = lane >> 2;                       // 0..15 row within 16-row chunk
    int schunk = (lane & 3) ^ ((lane >> 3) & 3);  // XOR-swizzled 16B chunk
    // reader swizzle slot (row ≡ l15 mod 16 for all frag rows)
    int rslot = (quad ^ ((l15 >> 1) & 3)) * 8;

    facc acc[4][4];
    for (int mi = 0; mi < 4; ++mi)
        for (int ni = 0; ni < 4; ++ni)
            for (int r = 0; r < 4; ++r) acc[mi][ni][r] = 0.f;

    for (int k0 = 0; k0 < K; k0 += 32) {
        for (int j = 0; j < 2; ++j) {
            int row = w * 32 + j * 16 + srow;     // 0..127
            gl_lds16(A  + (size_t)(m0 + row) * K + k0 + schunk * 8, &sm.s.A[w * 32 + j * 16][0]);
            gl_lds16(Bt + (size_t)(n0 + row) * K + k0 + schunk * 8, &sm.s.B[w * 32 + j * 16][0]);
        }
        __syncthreads();
        bfrag af[4], bf[4];
        for (int mi = 0; mi < 4; ++mi) af[mi] = *(const bfrag*)&sm.s.A[wm + mi * 16 + l15][rslot];
        for (int ni = 0; ni < 4; ++ni) bf[ni] = *(const bfrag*)&sm.s.B[wn + ni * 16 + l15][rslot];
        for (int mi = 0; mi < 4; ++mi)
            for (int ni = 0; ni < 4; ++ni)
                acc[mi][ni] = __builtin_amdgcn_mfma_f32_16x16x32_bf16(af[mi], bf[ni], acc[mi][ni], 0, 0, 0);
        __syncthreads();
    }

    // epilogue: 4 rounds; round t stages every wave's mi=t subtile (32x128)
    // then stores coalesced rows. C/D layout: col=l15, row=quad*4+r.
    for (int t = 0; t < 4; ++t) {
        __syncthreads();
        for (int ni = 0; ni < 4; ++ni)
            for (int r = 0; r < 4; ++r) {
                int lr = (w >> 1) * 16 + quad * 4 + r;
                int lc = wn + ni * 16 + l15;
                if (outF) sm.ctf[lr][lc] = acc[t][ni][r];
                else      sm.ct [lr][lc] = f2b(acc[t][ni][r]);
            }
        __syncthreads();
        if (outF) {
            for (int i = 0; i < 4; ++i) {
                int cc = tid + i * 256;
                int lr = cc >> 5, c4 = (cc & 31) * 4;
                int grow = m0 + (lr >> 4) * 64 + t * 16 + (lr & 15);
                *(float4*)((float*)Cmat + (size_t)grow * N + n0 + c4) =
                    *(const float4*)&sm.ctf[lr][c4];
            }
        } else {
            for (int i = 0; i < 2; ++i) {
                int cc = tid + i * 256;
                int lr = cc >> 4, c8 = (cc & 15) * 8;
                int grow = m0 + (lr >> 4) * 64 + t * 16 + (lr & 15);
                *(uint4*)((unsigned short*)Cmat + (size_t)grow * N + n0 + c8) =
                    *(const uint4*)&sm.ct[lr][c8];
            }
        }
    }
}

// ---------------------------------------------------------------------------
// RoPE in-place on bf16 X (8192 rows, stride elems/row, nh heads of 128).
// ---------------------------------------------------------------------------
__global__ __launch_bounds__(256) void k_rope(unsigned short* __restrict__ X,
                                              int lognh, int stride,
                                              const int* __restrict__ posPtr) {
    int tid = blockIdx.x * 256 + threadIdx.x;
    int d = tid & 63;
    int nh = 1 << lognh;
    int h = (tid >> 6) & (nh - 1);
    int row = tid >> (6 + lognh);
    int t = row & (TT - 1);
    float p = (float)(*posPtr + t);
    size_t base = (size_t)row * stride + h * 128 + d;
    union { unsigned int i; float f; } a, b2;
    a.i  = ((unsigned int)X[base]) << 16;
    b2.i = ((unsigned int)X[base + 64]) << 16;
    float x1 = a.f, x2 = b2.f;
    int i1 = d >> 1;
    // inv_freq = 10000^(-2i/128) = exp2(-i * 2*log2(1e4)/128)
    float f1 = exp2f(-(float)i1 * 0.20762050595278f);
    float f2 = exp2f(-(float)(i1 + 32) * 0.20762050595278f);
    float th1 = p * f1, th2 = p * f2;
    X[base]      = f2b(x1 * cosf(th1) - x2 * sinf(th1));
    X[base + 64] = f2b(x2 * cosf(th2) + x1 * sinf(th2));
}

// ---------------------------------------------------------------------------
// Flash attention, causal, GQA (16 q / 4 kv heads). Grid (T/64, B*16).
// K from KV buffer (stride 1024, cols 0..511); V from VbT (pre-transposed,
// 512 x 8192) so both stage as pure uint4. 2 barriers per K-step; the P
// LDS round-trip is wave-local (s_waitcnt lgkmcnt(0)). In-place att==Q.
// ---------------------------------------------------------------------------
__global__ __launch_bounds__(256) void k_flash(const unsigned short* __restrict__ Q,
                                               const unsigned short* __restrict__ KV,
                                               const unsigned short* __restrict__ VbT,
                                               unsigned short* __restrict__ att) {
    __shared__ alignas(16) unsigned short Ks[32][136];
    __shared__ alignas(16) unsigned short Vt[128][40];
    __shared__ alignas(16) unsigned short Pt[4][16][40];
    int tid = threadIdx.x;
    int w = tid >> 6, lane = tid & 63, quad = lane >> 4, l15 = lane & 15;
    int bh = blockIdx.y;
    int b = bh >> 4, h = bh & 15;
    int kvh = h >> 2;
    int qbase = blockIdx.x * 64;

    bfrag qf[4];
    {
        size_t qrow = (size_t)(b * TT + qbase + w * 16 + l15);
        for (int kc = 0; kc < 4; ++kc)
            qf[kc] = *(const bfrag*)(Q + qrow * 2048 + h * 128 + kc * 32 + quad * 8);
    }
    float mrow[4], lrow[4];
    facc o[8];
    for (int r = 0; r < 4; ++r) { mrow[r] = NEG_BIG; lrow[r] = 0.f; }
    for (int nb2 = 0; nb2 < 8; ++nb2)
        for (int r = 0; r < 4; ++r) o[nb2][r] = 0.f;

    const float sc = 0.08838834764831845f;   // 1/sqrt(128)
    int kmax = qbase + 64;
    for (int k0 = 0; k0 < kmax; k0 += 32) {
        for (int i = 0; i < 2; ++i) {
            int c = tid + i * 256;
            int krow = c >> 4, d8 = (c & 15) * 8;
            *(uint4*)&Ks[krow][d8] =
                *(const uint4*)(KV + (size_t)(b * TT + k0 + krow) * 1024 + kvh * 128 + d8);
            int vd = c >> 2, tc = (c & 3) * 8;
            *(uint4*)&Vt[vd][tc] =
                *(const uint4*)(VbT + (size_t)(kvh * 128 + vd) * 8192 + b * TT + k0 + tc);
        }
        __syncthreads();

        facc s[2];
        for (int nb = 0; nb < 2; ++nb) {
            for (int r = 0; r < 4; ++r) s[nb][r] = 0.f;
            for (int kc = 0; kc < 4; ++kc) {
                bfrag kf = *(const bfrag*)&Ks[nb * 16 + l15][kc * 32 + quad * 8];
                s[nb] = __builtin_amdgcn_mfma_f32_16x16x32_bf16(qf[kc], kf, s[nb], 0, 0, 0);
            }
        }

        float pv0[4], pv1[4];
        for (int r = 0; r < 4; ++r) {
            int qg = qbase + w * 16 + quad * 4 + r;
            bool msk0 = (k0 + l15 > qg);
            bool msk1 = (k0 + 16 + l15 > qg);
            float v0 = msk0 ? NEG_BIG : s[0][r] * sc;
            float v1 = msk1 ? NEG_BIG : s[1][r] * sc;
            float mx = fmaxf(v0, v1);
            for (int off = 1; off < 16; off <<= 1) mx = fmaxf(mx, __shfl_xor(mx, off, 64));
            float mnew = fmaxf(mrow[r], mx);
            float alpha = __expf(mrow[r] - mnew);
            float p0 = msk0 ? 0.f : __expf(v0 - mnew);
            float p1 = msk1 ? 0.f : __expf(v1 - mnew);
            float psum = p0 + p1;
            for (int off = 1; off < 16; off <<= 1) psum += __shfl_xor(psum, off, 64);
            lrow[r] = lrow[r] * alpha + psum;
            mrow[r] = mnew;
            for (int nb2 = 0; nb2 < 8; ++nb2) o[nb2][r] *= alpha;
            pv0[r] = p0; pv1[r] = p1;
        }

        for (int r = 0; r < 4; ++r) {
            Pt[w][quad * 4 + r][l15]      = f2b(pv0[r]);
            Pt[w][quad * 4 + r][16 + l15] = f2b(pv1[r]);
        }
        asm volatile("s_waitcnt lgkmcnt(0)" ::: "memory");   // wave-local RAW on Pt[w]
        bfrag pf = *(const bfrag*)&Pt[w][l15][quad * 8];
        for (int nb2 = 0; nb2 < 8; ++nb2) {
            bfrag vf = *(const bfrag*)&Vt[nb2 * 16 + l15][quad * 8];
            o[nb2] = __builtin_amdgcn_mfma_f32_16x16x32_bf16(pf, vf, o[nb2], 0, 0, 0);
        }
        __syncthreads();
    }

    for (int nb2 = 0; nb2 < 8; ++nb2)
        for (int r = 0; r < 4; ++r) {
            int qg = qbase + w * 16 + quad * 4 + r;
            att[(size_t)(b * TT + qg) * 2048 + h * 128 + nb2 * 16 + l15] =
                f2b(o[nb2][r] / lrow[r]);
        }
}

// ---------------------------------------------------------------------------
extern "C" void kernel_launch(void* const* d_in, const int* in_sizes, int n_in,
                              void* d_out, int out_size, void* d_ws, size_t ws_size,
                              hipStream_t stream) {
    const float* x  = (const float*)d_in[0];
    const float* Wq = (const float*)d_in[1];
    const float* Wk = (const float*)d_in[2];
    const float* Wv = (const float*)d_in[3];
    const float* Wo = (const float*)d_in[4];
    const int* pos  = (const int*)d_in[5];

    char* ws = (char*)d_ws;
    unsigned short* xb   = (unsigned short*)(ws + 0);          // 32 MB (8192x2048)
    unsigned short* Qb   = (unsigned short*)(ws + 33554432);   // 32 MB (8192x2048)
    unsigned short* KVb  = (unsigned short*)(ws + 67108864);   // 16 MB (8192x1024)
    unsigned short* VbT  = (unsigned short*)(ws + 83886080);   //  8 MB (512x8192)
    unsigned short* WqT  = (unsigned short*)(ws + 92274688);   //  8 MB (2048x2048)
    unsigned short* WkvT = (unsigned short*)(ws + 100663296);  //  4 MB (1024x2048)
    unsigned short* WoT  = (unsigned short*)(ws + 104857600);  //  8 MB -> 108 MB total

    // bf16 conversion + weight transposes (W is KxN; WT is NxK = B^T form)
    k_cvt<<<8192, 256, 0, stream>>>(x, xb, 2097152);
    k_wt<<<dim3(32, 32), 256, 0, stream>>>(Wq, WqT, 2048);
    k_wt<<<dim3(8, 32),  256, 0, stream>>>(Wk, WkvT, 512);
    k_wt<<<dim3(8, 32),  256, 0, stream>>>(Wv, WkvT + (size_t)512 * 2048, 512);
    k_wt<<<dim3(32, 32), 256, 0, stream>>>(Wo, WoT, 2048);

    // projections (Q; K|V fused)
    k_gemm_bt<<<dim3(16, 64), 256, 0, stream>>>(xb, WqT,  Qb,  8192, 2048, 2048, 0);
    k_gemm_bt<<<dim3(8, 64),  256, 0, stream>>>(xb, WkvT, KVb, 8192, 1024, 2048, 0);

    // RoPE (Q: 16 heads over stride 2048; K: 4 heads over stride 1024)
    k_rope<<<32768, 256, 0, stream>>>(Qb,  4, 2048, pos);
    k_rope<<<8192,  256, 0, stream>>>(KVb, 2, 1024, pos);

    // V transpose for flash B-frag staging
    k_vt<<<dim3(8, 128), 256, 0, stream>>>(KVb, VbT);

    // causal GQA flash attention, in-place over Qb
    k_flash<<<dim3(32, 64), 256, 0, stream>>>(Qb, KVb, VbT, Qb);

    // output projection -> fp32 d_out
    k_gemm_bt<<<dim3(16, 64), 256, 0, stream>>>(Qb, WoT, d_out, 8192, 2048, 2048, 1);
}